// Round 2
// baseline (7354.843 us; speedup 1.0000x reference)
//
#include <hip/hip_runtime.h>
#include <hip/hip_fp16.h>

#define T_LEN 1024
#define B_SZ  32
#define D_IN  768
#define H_SZ  768
#define G4    3072   // 4*H
#define FPAD  32     // flag padding: 1 flag per 128-byte line
#define LDA   40     // xg_gemm: padded LDS row stride (bf16) for 32-wide K tiles
#define HPAD  776    // lstm_rec: padded row stride (bf16 elems): 1552B = 4 banks/row -> 2-way max

typedef __attribute__((ext_vector_type(8))) short short8;  // 8 bf16 (4 VGPRs)
typedef __attribute__((ext_vector_type(4))) float f32x4;   // MFMA 16x16 C/D frag

// bitwise fp32 -> bf16 hi/lo split (exact residual; 3-term MFMA error ~2^-16 rel)
__device__ __forceinline__ void split2(float x0, float x1, unsigned& hp, unsigned& lp)
{
    const unsigned u0 = __float_as_uint(x0);
    const unsigned u1 = __float_as_uint(x1);
    const unsigned h0 = u0 & 0xffff0000u, h1 = u1 & 0xffff0000u;
    hp = (h0 >> 16) | h1;
    const float l0 = x0 - __uint_as_float(h0);
    const float l1 = x1 - __uint_as_float(h1);
    lp = (__float_as_uint(l0) >> 16) | (__float_as_uint(l1) & 0xffff0000u);
}

// ---------------------------------------------------------------------------
// Phase A: xg[(t*32+b)][g] = hidden[b][t][:] . W_ih[g][:] + b_ih[g] + b_hh[g]
// Split-bf16 3-term MFMA GEMM (verified R1: ~0.36 ms, absmax unchanged).
// ---------------------------------------------------------------------------
__global__ __launch_bounds__(256, 2)
void xg_gemm(const float* __restrict__ hidden, const float* __restrict__ W_ih,
             const float* __restrict__ b_ih, const float* __restrict__ b_hh,
             __half* __restrict__ xg)
{
    __shared__ unsigned short Ah[128 * LDA];
    __shared__ unsigned short Al[128 * LDA];
    __shared__ unsigned short Bh[128 * LDA];
    __shared__ unsigned short Bl[128 * LDA];

    const int tid = threadIdx.x;
    const int n0 = blockIdx.x * 128;
    const int m0 = blockIdx.y * 128;

    const int srow = tid >> 1;
    const int skh  = (tid & 1) * 16;
    const int m = m0 + srow;
    const float* arow = hidden + ((size_t)(m & 31) * T_LEN + (m >> 5)) * D_IN;
    const float* brow = W_ih + (size_t)(n0 + srow) * D_IN;

    const int lane = tid & 63;
    const int wid  = tid >> 6;
    const int wm = (wid >> 1) * 64;
    const int wn = (wid & 1) * 64;
    const int fr = lane & 15;
    const int fk = (lane >> 4) * 8;

    f32x4 acc[4][4];
#pragma unroll
    for (int i = 0; i < 4; ++i)
#pragma unroll
        for (int j = 0; j < 4; ++j) acc[i][j] = (f32x4)0.f;

    float4 av[4], bv[4];
#pragma unroll
    for (int q = 0; q < 4; ++q) {
        av[q] = *(const float4*)(arow + skh + 4 * q);
        bv[q] = *(const float4*)(brow + skh + 4 * q);
    }

    for (int kb = 0; kb < D_IN; kb += 32) {
        __syncthreads();
        {
            const float* f = (const float*)av;
            unsigned hp[8], lp[8];
#pragma unroll
            for (int p = 0; p < 8; ++p) split2(f[2 * p], f[2 * p + 1], hp[p], lp[p]);
            *(uint4*)&Ah[srow * LDA + skh]     = make_uint4(hp[0], hp[1], hp[2], hp[3]);
            *(uint4*)&Ah[srow * LDA + skh + 8] = make_uint4(hp[4], hp[5], hp[6], hp[7]);
            *(uint4*)&Al[srow * LDA + skh]     = make_uint4(lp[0], lp[1], lp[2], lp[3]);
            *(uint4*)&Al[srow * LDA + skh + 8] = make_uint4(lp[4], lp[5], lp[6], lp[7]);
        }
        {
            const float* f = (const float*)bv;
            unsigned hp[8], lp[8];
#pragma unroll
            for (int p = 0; p < 8; ++p) split2(f[2 * p], f[2 * p + 1], hp[p], lp[p]);
            *(uint4*)&Bh[srow * LDA + skh]     = make_uint4(hp[0], hp[1], hp[2], hp[3]);
            *(uint4*)&Bh[srow * LDA + skh + 8] = make_uint4(hp[4], hp[5], hp[6], hp[7]);
            *(uint4*)&Bl[srow * LDA + skh]     = make_uint4(lp[0], lp[1], lp[2], lp[3]);
            *(uint4*)&Bl[srow * LDA + skh + 8] = make_uint4(lp[4], lp[5], lp[6], lp[7]);
        }
        __syncthreads();

        if (kb + 32 < D_IN) {
#pragma unroll
            for (int q = 0; q < 4; ++q) {
                av[q] = *(const float4*)(arow + kb + 32 + skh + 4 * q);
                bv[q] = *(const float4*)(brow + kb + 32 + skh + 4 * q);
            }
        }

        short8 afh[4], afl[4], bfh[4], bfl[4];
#pragma unroll
        for (int i = 0; i < 4; ++i) {
            afh[i] = *(const short8*)&Ah[(wm + i * 16 + fr) * LDA + fk];
            afl[i] = *(const short8*)&Al[(wm + i * 16 + fr) * LDA + fk];
            bfh[i] = *(const short8*)&Bh[(wn + i * 16 + fr) * LDA + fk];
            bfl[i] = *(const short8*)&Bl[(wn + i * 16 + fr) * LDA + fk];
        }
#pragma unroll
        for (int i = 0; i < 4; ++i)
#pragma unroll
            for (int j = 0; j < 4; ++j) {
                acc[i][j] = __builtin_amdgcn_mfma_f32_16x16x32_bf16(afh[i], bfh[j], acc[i][j], 0, 0, 0);
                acc[i][j] = __builtin_amdgcn_mfma_f32_16x16x32_bf16(afh[i], bfl[j], acc[i][j], 0, 0, 0);
                acc[i][j] = __builtin_amdgcn_mfma_f32_16x16x32_bf16(afl[i], bfh[j], acc[i][j], 0, 0, 0);
            }
    }

    float biasv[4];
#pragma unroll
    for (int j = 0; j < 4; ++j) {
        const int col = n0 + wn + j * 16 + fr;
        biasv[j] = b_ih[col] + b_hh[col];
    }
    const int rbase = (lane >> 4) * 4;
#pragma unroll
    for (int i = 0; i < 4; ++i)
#pragma unroll
        for (int j = 0; j < 4; ++j) {
            const int col = n0 + wn + j * 16 + fr;
#pragma unroll
            for (int r = 0; r < 4; ++r) {
                const int row = m0 + wm + i * 16 + rbase + r;
                xg[(size_t)row * G4 + col] = __float2half_rn(acc[i][j][r] + biasv[j]);
            }
        }
}

// ---------------------------------------------------------------------------
__global__ void zero_cnt(unsigned* flags) {
    flags[blockIdx.x * 1024 + threadIdx.x] = 0u;
}

// fast tanh via v_exp_f32; ~1e-7 abs error, no overflow (e<=1).
__device__ __forceinline__ float fast_tanh(float x) {
    const float e = __expf(-2.f * fabsf(x));
    const float r = __fdividef(1.f - e, 1.f + e);
    return copysignf(r, x);
}

// ---------------------------------------------------------------------------
// Phase B: persistent cooperative recurrence.
// R5: recurrent dot h @ Whh^T moved to split-bf16 3-term MFMA.
//  - Whh slice (24 rows x 768) pre-split once into LDS bf16 hi/lo, stride
//    HPAD=776 (1552 B/row = 4 banks -> worst 2-way conflict = free).
//  - h staged per step as bf16 hi/lo (same split), from relaxed agent dword
//    loads of out[t-1] (coherence-point bypass; protocol unchanged).
//  - Each wave computes a K-quarter (192) via 16x16x32 MFMAs: 2 row tiles
//    (rows 0-15, 8-23 overlapped) x 6 k-steps x 3 split terms = 36 MFMA.
//  - 4-way cross-wave K-reduce through an 8 KB LDS buffer -> G[24][16].
//  - Split-phase poll: wait flags[0:64) -> stage h[k<384] -> wait flags[64:128)
//    -> stage h[k>=384]; straggler tail hides under first-half L3 loads.
//    (Safe: h[k] is read only after its producing WG's flag >= t.)
// ---------------------------------------------------------------------------
__global__ void __launch_bounds__(256, 1)
lstm_rec(const __half* __restrict__ xg, const float* __restrict__ Whh,
         float* __restrict__ out, unsigned* __restrict__ flags)
{
    extern __shared__ char smc[];
    unsigned short* Wh_s = (unsigned short*)smc;                 // 24*776*2 = 37248
    unsigned short* Wl_s = (unsigned short*)(smc + 37248);       // 37248
    unsigned short* Hh_s = (unsigned short*)(smc + 74496);       // 16*776*2 = 24832
    unsigned short* Hl_s = (unsigned short*)(smc + 99328);       // 24832
    float*          rbuf = (float*)(smc + 124160);               // 512*4*4 = 8192
    float*          G    = (float*)(smc + 132352);               // 384*4 = 1536 -> 133888

    const int tid = threadIdx.x;
    const int wg  = blockIdx.x;
    const int c   = wg & 1;        // batch group (sync domain)
    const int r   = wg >> 1;       // unit group 0..127
    const int u0  = r * 6;
    const int b0  = c * 16;

    // ---- load + split W_hh slice once: rows (gate*768 + u0 + j) ----
    for (int i = tid; i < 24 * 192; i += 256) {
        const int rr = i / 192;              // local row 0..23
        const int kc = (i % 192) * 4;
        const int gate = rr / 6, j = rr % 6;
        const float4 v = *(const float4*)&Whh[(size_t)(gate * H_SZ + u0 + j) * H_SZ + kc];
        unsigned h01, l01, h23, l23;
        split2(v.x, v.y, h01, l01);
        split2(v.z, v.w, h23, l23);
        *(uint2*)&Wh_s[rr * HPAD + kc] = make_uint2(h01, h23);
        *(uint2*)&Wl_s[rr * HPAD + kc] = make_uint2(l01, l23);
    }

    // MFMA roles
    const int lane = tid & 63;
    const int wv   = tid >> 6;               // wave = K-quarter owner
    const int fr   = lane & 15;              // frag row (W) / row (h=batch)
    const int fkb  = (lane >> 4) * 8;        // frag k offset
    const int rb4  = (lane >> 4) * 4;        // D frag row base

    // combine-phase role (threads 0..95)
    const int cj = tid % 6;                  // unit within group
    const int cb = tid / 6;                  // batch within group
    float c_reg = 0.f;                       // cell state, register-resident

    unsigned* myflags = flags + c * 128 * FPAD;

    __builtin_amdgcn_fence(__ATOMIC_ACQUIRE, "agent");  // once: clear poison
    __syncthreads();

    for (int t = 0; t < T_LEN; ++t) {
        // ---- prefetch xg[t] for the combine (independent of h) ----
        float xpi = 0.f, xpf = 0.f, xpg = 0.f, xpo = 0.f;
        if (tid < 96) {
            const size_t xbase = ((size_t)t * B_SZ + (b0 + cb)) * G4 + u0 + cj;
            xpi = __half2float(xg[xbase + 0 * H_SZ]);
            xpf = __half2float(xg[xbase + 1 * H_SZ]);
            xpg = __half2float(xg[xbase + 2 * H_SZ]);
            xpo = __half2float(xg[xbase + 3 * H_SZ]);
        }

        if (t == 0) {
            for (int i = tid; i < 384; i += 256) G[i] = 0.f;  // h_prev = 0
            __syncthreads();
        } else {
            // ---- phase A: wait producers of h[k<384] (WGs r<64) ----
            if (tid < 64) {
                while (__hip_atomic_load(&myflags[tid * FPAD], __ATOMIC_RELAXED,
                                         __HIP_MEMORY_SCOPE_AGENT) < (unsigned)t) {
                    __builtin_amdgcn_s_sleep(2);
                }
            }
            __syncthreads();

            // ---- stage h halves: load (agent dword, bypass), split, LDS ----
#pragma unroll
            for (int half = 0; half < 2; ++half) {
                float xv[6][4];
#pragma unroll
                for (int it = 0; it < 6; ++it) {
                    const int g = it * 256 + tid;      // 0..1535
                    const int b = g / 96;
                    const int k = half * 384 + (g - b * 96) * 4;
                    const float* src = &out[((size_t)(b0 + b) * T_LEN + (t - 1)) * H_SZ + k];
#pragma unroll
                    for (int q = 0; q < 4; ++q)
                        xv[it][q] = __hip_atomic_load(src + q, __ATOMIC_RELAXED,
                                                      __HIP_MEMORY_SCOPE_AGENT);
                }
#pragma unroll
                for (int it = 0; it < 6; ++it) {
                    const int g = it * 256 + tid;
                    const int b = g / 96;
                    const int k = half * 384 + (g - b * 96) * 4;
                    unsigned h01, l01, h23, l23;
                    split2(xv[it][0], xv[it][1], h01, l01);
                    split2(xv[it][2], xv[it][3], h23, l23);
                    *(uint2*)&Hh_s[b * HPAD + k] = make_uint2(h01, h23);
                    *(uint2*)&Hl_s[b * HPAD + k] = make_uint2(l01, l23);
                }
                if (half == 0) {
                    // ---- phase B: wait producers of h[k>=384] (WGs r>=64);
                    //      straggler tail hidden under the half-1 loads ----
                    if (tid >= 64 && tid < 128) {
                        while (__hip_atomic_load(&myflags[tid * FPAD], __ATOMIC_RELAXED,
                                                 __HIP_MEMORY_SCOPE_AGENT) < (unsigned)t) {
                            __builtin_amdgcn_s_sleep(2);
                        }
                    }
                    __syncthreads();
                }
            }
            __syncthreads();

            // ---- dot via MFMA: wave wv owns k in [192*wv, 192*wv+192) ----
            f32x4 acc0 = (f32x4)0.f, acc1 = (f32x4)0.f;
            const int kwb = wv * 192;
#pragma unroll
            for (int ksd = 0; ksd < 6; ++ksd) {
                const int ko = kwb + ksd * 32 + fkb;
                const short8 bh  = *(const short8*)&Hh_s[fr * HPAD + ko];
                const short8 bl  = *(const short8*)&Hl_s[fr * HPAD + ko];
                const short8 a0h = *(const short8*)&Wh_s[fr * HPAD + ko];
                const short8 a0l = *(const short8*)&Wl_s[fr * HPAD + ko];
                const short8 a1h = *(const short8*)&Wh_s[(8 + fr) * HPAD + ko];
                const short8 a1l = *(const short8*)&Wl_s[(8 + fr) * HPAD + ko];
                acc0 = __builtin_amdgcn_mfma_f32_16x16x32_bf16(a0h, bh, acc0, 0, 0, 0);
                acc0 = __builtin_amdgcn_mfma_f32_16x16x32_bf16(a0h, bl, acc0, 0, 0, 0);
                acc0 = __builtin_amdgcn_mfma_f32_16x16x32_bf16(a0l, bh, acc0, 0, 0, 0);
                acc1 = __builtin_amdgcn_mfma_f32_16x16x32_bf16(a1h, bh, acc1, 0, 0, 0);
                acc1 = __builtin_amdgcn_mfma_f32_16x16x32_bf16(a1h, bl, acc1, 0, 0, 0);
                acc1 = __builtin_amdgcn_mfma_f32_16x16x32_bf16(a1l, bh, acc1, 0, 0, 0);
            }

            // ---- cross-wave K-reduce: rbuf[(tile*16+row_d)*16+col][wave] ----
#pragma unroll
            for (int rix = 0; rix < 4; ++rix) {
                rbuf[((rb4 + rix) * 16 + fr) * 4 + wv]      = acc0[rix];
                rbuf[((16 + rb4 + rix) * 16 + fr) * 4 + wv] = acc1[rix];
            }
            __syncthreads();
            for (int oi = tid; oi < 384; oi += 256) {
                const int row = oi >> 4, colr = oi & 15;
                // rows 0-15 from tile0; rows 16-23 from tile1 (row_d=row-8)
                const int idx = (row < 16) ? oi : ((row + 8) * 16 + colr);
                const float4 v = *(const float4*)&rbuf[idx * 4];
                G[oi] = v.x + v.y + v.z + v.w;
            }
            __syncthreads();
        }

        // ---- gate combine: threads 0..95, one (unit, batch) each ----
        if (tid < 96) {
            const float pi = G[(0 * 6 + cj) * 16 + cb] + xpi;
            const float pf = G[(1 * 6 + cj) * 16 + cb] + xpf;
            const float pg = G[(2 * 6 + cj) * 16 + cb] + xpg;
            const float po = G[(3 * 6 + cj) * 16 + cb] + xpo;
            const float ig = 1.f / (1.f + __expf(-pi));
            const float fg = 1.f / (1.f + __expf(-pf));
            const float gg = fast_tanh(pg);
            const float og = 1.f / (1.f + __expf(-po));
            c_reg = fg * c_reg + ig * gg;
            const float h = og * fast_tanh(c_reg);
            __hip_atomic_store(&out[((size_t)(b0 + cb) * T_LEN + t) * H_SZ + u0 + cj],
                               h, __ATOMIC_RELAXED, __HIP_MEMORY_SCOPE_AGENT);
        }
        // drain vmem stores, then barrier so ALL waves' stores are done
        asm volatile("s_waitcnt vmcnt(0)" ::: "memory");
        __syncthreads();

        // ---- publish: one relaxed flag store (flag = steps completed) ----
        if (tid == 0) {
            __hip_atomic_store(&myflags[r * FPAD], (unsigned)(t + 1),
                               __ATOMIC_RELAXED, __HIP_MEMORY_SCOPE_AGENT);
        }
    }
}

// ---------------------------------------------------------------------------
extern "C" void kernel_launch(void* const* d_in, const int* in_sizes, int n_in,
                              void* d_out, int out_size, void* d_ws, size_t ws_size,
                              hipStream_t stream)
{
    (void)in_sizes; (void)n_in; (void)out_size; (void)ws_size;
    const float* hidden = (const float*)d_in[0];
    const float* W_ih   = (const float*)d_in[1];
    const float* W_hh   = (const float*)d_in[2];
    const float* b_ih   = (const float*)d_in[3];
    const float* b_hh   = (const float*)d_in[4];
    float* out = (float*)d_out;

    __half* xg = (__half*)d_ws;                                  // 201,326,592 B
    unsigned* flags = (unsigned*)((char*)d_ws +
                      (size_t)T_LEN * B_SZ * G4 * sizeof(__half)); // 8192 u32

    zero_cnt<<<dim3(8), dim3(1024), 0, stream>>>(flags);
    xg_gemm<<<dim3(G4 / 128, (B_SZ * T_LEN) / 128), dim3(256), 0, stream>>>(
        hidden, W_ih, b_ih, b_hh, xg);

    const int smem = 133888;   // Wh/Wl 74496 + Hh/Hl 49664 + rbuf 8192 + G 1536
    hipFuncSetAttribute((const void*)lstm_rec,
                        hipFuncAttributeMaxDynamicSharedMemorySize, smem);
    void* args[] = { (void*)&xg, (void*)&W_hh, (void*)&out, (void*)&flags };
    hipLaunchCooperativeKernel((void*)lstm_rec, dim3(256), dim3(256),
                               args, (unsigned)smem, stream);
}